// Round 4
// baseline (585.914 us; speedup 1.0000x reference)
//
#include <hip/hip_runtime.h>
#include <hip/hip_bf16.h>
#include <stdint.h>

#define D_MODEL 768
#define N_HEAD 12
#define D_HEAD 64
#define BATCH 4
#define SEQ 1024
#define HB 48
#define PROJ_ELEMS (BATCH * SEQ * D_MODEL)   // 3145728

typedef __attribute__((ext_vector_type(8))) short bf8_t;   // 8 bf16 = one MFMA A/B frag
typedef __attribute__((ext_vector_type(4))) float f4_t;    // 4 fp32 = one MFMA C/D frag

__device__ inline unsigned short f2b(float f) {           // RNE float->bf16
    union { float f; unsigned u; } v; v.f = f;
    unsigned r = v.u + 0x7FFFu + ((v.u >> 16) & 1u);
    return (unsigned short)(r >> 16);
}

// ---------------------------------------------------------------------------
// fp32 -> bf16 bulk convert (z picks one of up to 4 tensors)
// ---------------------------------------------------------------------------
__global__ __launch_bounds__(256) void cvt_k(
    const float* __restrict__ s0, const float* __restrict__ s1,
    const float* __restrict__ s2, const float* __restrict__ s3,
    unsigned short* __restrict__ d0, unsigned short* __restrict__ d1,
    unsigned short* __restrict__ d2, unsigned short* __restrict__ d3, int n)
{
    const int z = blockIdx.z;
    const float* s = (z == 0) ? s0 : (z == 1) ? s1 : (z == 2) ? s2 : s3;
    unsigned short* d = (z == 0) ? d0 : (z == 1) ? d1 : (z == 2) ? d2 : d3;
    int i = (blockIdx.x * 256 + threadIdx.x) * 4;
    if (i >= n) return;
    float4 v = *(const float4*)(s + i);
    ushort4 o;
    o.x = f2b(v.x); o.y = f2b(v.y); o.z = f2b(v.z); o.w = f2b(v.w);
    *(ushort4*)(d + i) = o;
}

// ---------------------------------------------------------------------------
// Zero the stats (row-sum) array: 48*1024 floats.
// ---------------------------------------------------------------------------
__global__ __launch_bounds__(256) void zero_stats(float* __restrict__ stats)
{
    int i = (blockIdx.x * 256 + threadIdx.x) * 4;
    float4 z = {0.f, 0.f, 0.f, 0.f};
    *(float4*)(stats + i) = z;
}

// ---------------------------------------------------------------------------
// QKV projection: Y = X * W^T + bias, bf16 MFMA, 128x128 tile, BK=64.
// Output head-split bf16: out[((h*4+b)*1024 + l)*64 + dh]
// ---------------------------------------------------------------------------
__global__ __launch_bounds__(256) void proj_mfma(
    const unsigned short* __restrict__ qb, const unsigned short* __restrict__ kb,
    const unsigned short* __restrict__ vb,
    const unsigned short* __restrict__ wqb, const unsigned short* __restrict__ wkb,
    const unsigned short* __restrict__ wvb,
    const float* __restrict__ bq, const float* __restrict__ bk, const float* __restrict__ bv,
    unsigned short* __restrict__ qh, unsigned short* __restrict__ kh,
    unsigned short* __restrict__ vh)
{
    const int z = blockIdx.z;
    const unsigned short* X = (z == 0) ? qb : (z == 1) ? kb : vb;
    const unsigned short* W = (z == 0) ? wqb : (z == 1) ? wkb : wvb;
    const float* bias = (z == 0) ? bq : (z == 1) ? bk : bv;
    unsigned short* Out = (z == 0) ? qh : (z == 1) ? kh : vh;

    const int m0 = blockIdx.y * 128;
    const int n0 = blockIdx.x * 128;

    __shared__ alignas(16) unsigned short As[128 * 72];   // row stride 72 shorts
    __shared__ alignas(16) unsigned short Bs[128 * 72];

    const int tid = threadIdx.x;
    const int wave = tid >> 6, lane = tid & 63;
    const int quad = lane >> 4, lq = lane & 15;
    const int wr = wave >> 1, wc = wave & 1;   // wave's 64x64 quadrant

    f4_t acc[4][4];
    #pragma unroll
    for (int i = 0; i < 4; ++i)
        #pragma unroll
        for (int j = 0; j < 4; ++j)
            #pragma unroll
            for (int r = 0; r < 4; ++r) acc[i][j][r] = 0.0f;

    for (int k0 = 0; k0 < D_MODEL; k0 += 64) {
        #pragma unroll
        for (int i = 0; i < 4; ++i) {
            int c = tid + 256 * i;            // 1024 16B-chunks per tile
            int row = c >> 3, off = (c & 7) * 8;
            *(bf8_t*)(As + row * 72 + off) =
                *(const bf8_t*)(X + (size_t)(m0 + row) * D_MODEL + k0 + off);
            *(bf8_t*)(Bs + row * 72 + off) =
                *(const bf8_t*)(W + (size_t)(n0 + row) * D_MODEL + k0 + off);
        }
        __syncthreads();
        #pragma unroll
        for (int ks = 0; ks < 2; ++ks) {
            bf8_t af[4], bfr[4];
            #pragma unroll
            for (int i = 0; i < 4; ++i)
                af[i] = *(const bf8_t*)(As + (wr * 64 + i * 16 + lq) * 72 + ks * 32 + quad * 8);
            #pragma unroll
            for (int j = 0; j < 4; ++j)
                bfr[j] = *(const bf8_t*)(Bs + (wc * 64 + j * 16 + lq) * 72 + ks * 32 + quad * 8);
            #pragma unroll
            for (int i = 0; i < 4; ++i)
                #pragma unroll
                for (int j = 0; j < 4; ++j)
                    acc[i][j] = __builtin_amdgcn_mfma_f32_16x16x32_bf16(af[i], bfr[j], acc[i][j], 0, 0, 0);
        }
        __syncthreads();
    }

    const int bb = m0 >> 10;
    #pragma unroll
    for (int j = 0; j < 4; ++j) {
        int col = n0 + wc * 64 + j * 16 + lq;
        float bv_ = bias[col];
        int h = col >> 6, dh = col & 63;
        #pragma unroll
        for (int i = 0; i < 4; ++i) {
            #pragma unroll
            for (int r = 0; r < 4; ++r) {
                int m = m0 + wr * 64 + i * 16 + quad * 4 + r;
                int l = m & 1023;
                Out[(((size_t)(h * BATCH + bb) * SEQ + l) << 6) + dh] = f2b(acc[i][j][r] + bv_);
            }
        }
    }
}

// ---------------------------------------------------------------------------
// Transpose V per (hb, t-tile): vT[hb][dh][t] from vh[hb][t][dh]
// ---------------------------------------------------------------------------
__global__ __launch_bounds__(256) void vtrans(
    const unsigned short* __restrict__ vh, unsigned short* __restrict__ vT)
{
    const int hb = blockIdx.y, tt = blockIdx.x;
    __shared__ alignas(16) unsigned short s[64 * 72];
    const int tid = threadIdx.x;
    #pragma unroll
    for (int i = 0; i < 2; ++i) {
        int c = tid + 256 * i;
        int t = c >> 3, off = (c & 7) * 8;
        *(bf8_t*)(s + t * 72 + off) =
            *(const bf8_t*)(vh + ((size_t)hb * SEQ + tt * 64 + t) * 64 + off);
    }
    __syncthreads();
    #pragma unroll
    for (int i = 0; i < 2; ++i) {
        int c = tid + 256 * i;
        int dh = c >> 3, toff = (c & 7) * 8;
        union { unsigned short u[8]; bf8_t v; } tmp;
        #pragma unroll
        for (int j = 0; j < 8; ++j) tmp.u[j] = s[(toff + j) * 72 + dh];
        *(bf8_t*)(vT + ((size_t)hb * 64 + dh) * SEQ + tt * 64 + toff) = tmp.v;
    }
}

// ---------------------------------------------------------------------------
// Fused loc + QK^T + mask -> UNNORMALIZED softmax terms in fused[h][b][l][t]:
//   term = max(relu(loc),1e-6) * exp(min(0.125*qk, 60)), masked -> 0.
// Identity: softmax(log(clip(loc)) + s) = term / rowsum(term).
// Row sums accumulated into stats[hb][l] via atomicAdd (pre-zeroed).
// Block: (b, l-tile 32, t-tile 64), loops all 12 heads; pl read ONCE.
// Wave w: l-half = w>>1, t-quarter pair = w&1 (2 16x16 S-tiles per wave).
// ---------------------------------------------------------------------------
__global__ __launch_bounds__(256) void attn_term(
    const unsigned short* __restrict__ qh, const unsigned short* __restrict__ kh,
    const float* __restrict__ pl, const int* __restrict__ mask,
    const float* __restrict__ wloc, const float* __restrict__ bloc,
    float* __restrict__ fused, float* __restrict__ stats)
{
    const int b = blockIdx.z;
    const int l0 = blockIdx.y * 32;
    const int t0 = blockIdx.x * 64;

    __shared__ alignas(16) float spl[32 * 324];            // [l][t*5], padded stride
    __shared__ alignas(16) unsigned short sq[32 * 72];
    __shared__ alignas(16) unsigned short sk[64 * 72];

    const int tid = threadIdx.x;
    {   // cooperative pl tile load: 32 rows x 320 floats = 2560 float4, 10/thread
        int r = tid >> 3, c8 = tid & 7;
        const float* src = pl + (((size_t)(b * SEQ + l0 + r) * SEQ) + t0) * 5;
        float* dst = spl + r * 324;
        #pragma unroll
        for (int j = 0; j < 10; ++j) {
            int f4i = j * 8 + c8;              // 0..79
            *(float4*)(dst + f4i * 4) = *(const float4*)(src + f4i * 4);
        }
    }
    const int wave = tid >> 6, lane = tid & 63;
    const int quad = lane >> 4, lq = lane & 15;
    const int lw = wave >> 1;                  // l-half (0..1)
    const int tq = wave & 1;                   // t-half (0..1), 2 tiles of 16 each
    const int mk0 = mask[b * SEQ + t0 + tq * 32 + lq];
    const int mk1 = mask[b * SEQ + t0 + tq * 32 + 16 + lq];

    for (int h = 0; h < N_HEAD; ++h) {
        const int hb = h * BATCH + b;
        {   // stage Q: 32 rows x 8 chunks = 256 (1/thread)
            int row = tid >> 3, off = (tid & 7) * 8;
            *(bf8_t*)(sq + row * 72 + off) =
                *(const bf8_t*)(qh + (((size_t)hb * SEQ) + l0 + row) * 64 + off);
        }
        #pragma unroll
        for (int i = 0; i < 2; ++i) {          // stage K: 64 rows x 8 chunks
            int c = tid + 256 * i;
            int r2 = c >> 3, o2 = (c & 7) * 8;
            *(bf8_t*)(sk + r2 * 72 + o2) =
                *(const bf8_t*)(kh + (((size_t)hb * SEQ) + t0 + r2) * 64 + o2);
        }
        __syncthreads();

        const float wl0 = wloc[h * 5 + 0], wl1 = wloc[h * 5 + 1], wl2 = wloc[h * 5 + 2];
        const float wl3 = wloc[h * 5 + 3], wl4 = wloc[h * 5 + 4];
        const float bl = bloc[h];

        bf8_t a0 = *(const bf8_t*)(sq + (lw * 16 + lq) * 72 + quad * 8);
        bf8_t a1 = *(const bf8_t*)(sq + (lw * 16 + lq) * 72 + 32 + quad * 8);

        float tsum[4] = {0.f, 0.f, 0.f, 0.f};  // per-row partial sums (rows lw*16+quad*4+r)

        #pragma unroll
        for (int tile2 = 0; tile2 < 2; ++tile2) {
            const int tcol = tq * 32 + tile2 * 16;      // tile-local t base
            bf8_t b0 = *(const bf8_t*)(sk + (tcol + lq) * 72 + quad * 8);
            bf8_t b1 = *(const bf8_t*)(sk + (tcol + lq) * 72 + 32 + quad * 8);
            f4_t acc = {0.f, 0.f, 0.f, 0.f};
            acc = __builtin_amdgcn_mfma_f32_16x16x32_bf16(a0, b0, acc, 0, 0, 0);
            acc = __builtin_amdgcn_mfma_f32_16x16x32_bf16(a1, b1, acc, 0, 0, 0);

            const int mk = tile2 ? mk1 : mk0;
            const int tt = tcol + lq;                    // tile-local t (0..63)
            #pragma unroll
            for (int r = 0; r < 4; ++r) {
                int ll = lw * 16 + quad * 4 + r;         // tile-local l (0..31)
                const float* p5 = spl + ll * 324 + tt * 5;
                float loc = fmaf(wl0, p5[0], fmaf(wl1, p5[1], fmaf(wl2, p5[2],
                            fmaf(wl3, p5[3], fmaf(wl4, p5[4], bl)))));
                loc = fmaxf(fmaxf(loc, 0.0f), 1e-6f);    // clip(relu(loc), 1e-6)
                float s = fminf(0.125f * acc[r], 60.0f);
                float term = mk ? 0.0f : loc * __expf(s);
                fused[((size_t)hb * SEQ + l0 + ll) * SEQ + t0 + tt] = term;
                tsum[r] += term;
            }
        }
        // reduce tsum across the 16 lanes of this quad (same row), then atomic
        #pragma unroll
        for (int r = 0; r < 4; ++r) {
            float s = tsum[r];
            #pragma unroll
            for (int o = 1; o < 16; o <<= 1) s += __shfl_xor(s, o, 64);
            if (lq == 0)
                atomicAdd(&stats[(size_t)hb * SEQ + l0 + lw * 16 + quad * 4 + r], s);
        }
        __syncthreads();
    }
}

// ---------------------------------------------------------------------------
// PV with fused normalization: P = term * (1/rowsum) written BACK to fused
// (the final output), and P (bf16) @ V via MFMA -> attn_out fp32 [b][l][768].
// ---------------------------------------------------------------------------
__global__ __launch_bounds__(256) void pv_scale(
    float* __restrict__ fused, const unsigned short* __restrict__ vT,
    const float* __restrict__ stats, float* __restrict__ attn_out)
{
    const int hb = blockIdx.y;
    const int l0 = blockIdx.x * 64;
    const int h = hb >> 2, b = hb & 3;

    __shared__ alignas(16) unsigned short sp[64 * 72];
    __shared__ alignas(16) unsigned short sv[64 * 72];
    __shared__ alignas(16) float sst[64];

    const int tid = threadIdx.x;
    if (tid < 64) sst[tid] = 1.0f / stats[(size_t)hb * SEQ + l0 + tid];
    const int wave = tid >> 6, lane = tid & 63;
    const int quad = lane >> 4, lq = lane & 15;

    f4_t acc[4];
    #pragma unroll
    for (int c = 0; c < 4; ++c)
        #pragma unroll
        for (int r = 0; r < 4; ++r) acc[c][r] = 0.f;
    __syncthreads();

    for (int tt = 0; tt < 16; ++tt) {
        #pragma unroll
        for (int i = 0; i < 4; ++i) {
            int c = tid + 256 * i;             // 1024 float4 chunks
            int row = c >> 4, f4i = c & 15;
            float* gp = fused + ((size_t)hb * SEQ + l0 + row) * SEQ + tt * 64 + f4i * 4;
            float4 v = *(const float4*)gp;
            float invS = sst[row];
            float4 pv;
            pv.x = v.x * invS;
            pv.y = v.y * invS;
            pv.z = v.z * invS;
            pv.w = v.w * invS;
            *(float4*)gp = pv;
            ushort4 pb;
            pb.x = f2b(pv.x); pb.y = f2b(pv.y); pb.z = f2b(pv.z); pb.w = f2b(pv.w);
            *(ushort4*)(sp + row * 72 + f4i * 4) = pb;
        }
        #pragma unroll
        for (int i = 0; i < 2; ++i) {
            int c = tid + 256 * i;
            int row = c >> 3, off = (c & 7) * 8;
            *(bf8_t*)(sv + row * 72 + off) =
                *(const bf8_t*)(vT + ((size_t)hb * 64 + row) * SEQ + tt * 64 + off);
        }
        __syncthreads();
        bf8_t af0 = *(const bf8_t*)(sp + (wave * 16 + lq) * 72 + quad * 8);
        bf8_t af1 = *(const bf8_t*)(sp + (wave * 16 + lq) * 72 + 32 + quad * 8);
        #pragma unroll
        for (int c = 0; c < 4; ++c) {
            bf8_t b0 = *(const bf8_t*)(sv + (c * 16 + lq) * 72 + quad * 8);
            bf8_t b1 = *(const bf8_t*)(sv + (c * 16 + lq) * 72 + 32 + quad * 8);
            acc[c] = __builtin_amdgcn_mfma_f32_16x16x32_bf16(af0, b0, acc[c], 0, 0, 0);
            acc[c] = __builtin_amdgcn_mfma_f32_16x16x32_bf16(af1, b1, acc[c], 0, 0, 0);
        }
        __syncthreads();
    }
    #pragma unroll
    for (int c = 0; c < 4; ++c)
        #pragma unroll
        for (int r = 0; r < 4; ++r) {
            int l = l0 + wave * 16 + quad * 4 + r;
            attn_out[((size_t)b * SEQ + l) * D_MODEL + h * 64 + c * 16 + lq] = acc[c][r];
        }
}

// ---------------------------------------------------------------------------
// FC: Out = X(fp32,cvt inline) * W^T + bias + residual -> fp32
// ---------------------------------------------------------------------------
__global__ __launch_bounds__(256) void fc_mfma(
    const float* __restrict__ X, const unsigned short* __restrict__ W,
    const float* __restrict__ bias, const float* __restrict__ residual,
    float* __restrict__ Out)
{
    const int m0 = blockIdx.y * 128;
    const int n0 = blockIdx.x * 128;

    __shared__ alignas(16) unsigned short As[128 * 72];
    __shared__ alignas(16) unsigned short Bs[128 * 72];

    const int tid = threadIdx.x;
    const int wave = tid >> 6, lane = tid & 63;
    const int quad = lane >> 4, lq = lane & 15;
    const int wr = wave >> 1, wc = wave & 1;

    f4_t acc[4][4];
    #pragma unroll
    for (int i = 0; i < 4; ++i)
        #pragma unroll
        for (int j = 0; j < 4; ++j)
            #pragma unroll
            for (int r = 0; r < 4; ++r) acc[i][j][r] = 0.0f;

    for (int k0 = 0; k0 < D_MODEL; k0 += 64) {
        #pragma unroll
        for (int i = 0; i < 4; ++i) {
            int c = tid + 256 * i;
            int row = c >> 3, off = (c & 7) * 8;
            const float* src = X + (size_t)(m0 + row) * D_MODEL + k0 + off;
            float4 u0 = *(const float4*)src;
            float4 u1 = *(const float4*)(src + 4);
            union { unsigned short u[8]; bf8_t v; } t;
            t.u[0] = f2b(u0.x); t.u[1] = f2b(u0.y); t.u[2] = f2b(u0.z); t.u[3] = f2b(u0.w);
            t.u[4] = f2b(u1.x); t.u[5] = f2b(u1.y); t.u[6] = f2b(u1.z); t.u[7] = f2b(u1.w);
            *(bf8_t*)(As + row * 72 + off) = t.v;
            *(bf8_t*)(Bs + row * 72 + off) =
                *(const bf8_t*)(W + (size_t)(n0 + row) * D_MODEL + k0 + off);
        }
        __syncthreads();
        #pragma unroll
        for (int ks = 0; ks < 2; ++ks) {
            bf8_t af[4], bfr[4];
            #pragma unroll
            for (int i = 0; i < 4; ++i)
                af[i] = *(const bf8_t*)(As + (wr * 64 + i * 16 + lq) * 72 + ks * 32 + quad * 8);
            #pragma unroll
            for (int j = 0; j < 4; ++j)
                bfr[j] = *(const bf8_t*)(Bs + (wc * 64 + j * 16 + lq) * 72 + ks * 32 + quad * 8);
            #pragma unroll
            for (int i = 0; i < 4; ++i)
                #pragma unroll
                for (int j = 0; j < 4; ++j)
                    acc[i][j] = __builtin_amdgcn_mfma_f32_16x16x32_bf16(af[i], bfr[j], acc[i][j], 0, 0, 0);
        }
        __syncthreads();
    }

    #pragma unroll
    for (int j = 0; j < 4; ++j) {
        int col = n0 + wc * 64 + j * 16 + lq;
        float bv_ = bias[col];
        #pragma unroll
        for (int i = 0; i < 4; ++i) {
            #pragma unroll
            for (int r = 0; r < 4; ++r) {
                int m = m0 + wr * 64 + i * 16 + quad * 4 + r;
                Out[(size_t)m * D_MODEL + col] =
                    acc[i][j][r] + bv_ + residual[(size_t)m * D_MODEL + col];
            }
        }
    }
}

// ---------------------------------------------------------------------------
// LayerNorm over 768 per row -> d_out
// ---------------------------------------------------------------------------
__global__ __launch_bounds__(256) void ln_k(
    const float* __restrict__ X, const float* __restrict__ g,
    const float* __restrict__ bta, float* __restrict__ out)
{
    const int row = blockIdx.x;
    const float* x = X + (size_t)row * D_MODEL;
    const int tid = threadIdx.x;
    const int lane = tid & 63, wid = tid >> 6;
    __shared__ float s1[4], s2[4];

    float v0 = x[tid], v1 = x[tid + 256], v2 = x[tid + 512];
    float s = v0 + v1 + v2;
    float q = v0 * v0 + v1 * v1 + v2 * v2;
    #pragma unroll
    for (int o = 32; o > 0; o >>= 1) {
        s += __shfl_down(s, o, 64);
        q += __shfl_down(q, o, 64);
    }
    if (lane == 0) { s1[wid] = s; s2[wid] = q; }
    __syncthreads();
    const float sum = s1[0] + s1[1] + s1[2] + s1[3];
    const float sq  = s2[0] + s2[1] + s2[2] + s2[3];
    const float mu = sum * (1.0f / D_MODEL);
    const float var = sq * (1.0f / D_MODEL) - mu * mu;
    const float r = rsqrtf(var + 1e-5f);

    float* o = out + (size_t)row * D_MODEL;
    o[tid]       = (v0 - mu) * r * g[tid]       + bta[tid];
    o[tid + 256] = (v1 - mu) * r * g[tid + 256] + bta[tid + 256];
    o[tid + 512] = (v2 - mu) * r * g[tid + 512] + bta[tid + 512];
}

// ---------------------------------------------------------------------------
extern "C" void kernel_launch(void* const* d_in, const int* in_sizes, int n_in,
                              void* d_out, int out_size, void* d_ws, size_t ws_size,
                              hipStream_t stream)
{
    const float* q    = (const float*)d_in[0];
    const float* k    = (const float*)d_in[1];
    const float* v    = (const float*)d_in[2];
    const float* pl   = (const float*)d_in[3];
    const int*   mask = (const int*)d_in[4];
    const float* wq   = (const float*)d_in[5];
    const float* bq   = (const float*)d_in[6];
    const float* wk   = (const float*)d_in[7];
    const float* bk   = (const float*)d_in[8];
    const float* wv   = (const float*)d_in[9];
    const float* bv   = (const float*)d_in[10];
    const float* wfc  = (const float*)d_in[11];
    const float* bfc  = (const float*)d_in[12];
    const float* wloc = (const float*)d_in[13];
    const float* bloc = (const float*)d_in[14];
    const float* lng  = (const float*)d_in[15];
    const float* lnb  = (const float*)d_in[16];

    char* W8 = (char*)d_ws;
    const size_t SLOT = (size_t)PROJ_ELEMS * 2;            // 6291456 B per bf16 tensor
    unsigned short* qb   = (unsigned short*)(W8 + 0 * SLOT);
    unsigned short* kb   = (unsigned short*)(W8 + 1 * SLOT);
    unsigned short* vb   = (unsigned short*)(W8 + 2 * SLOT);
    unsigned short* qh   = (unsigned short*)(W8 + 3 * SLOT);
    unsigned short* kh   = (unsigned short*)(W8 + 4 * SLOT);
    unsigned short* vh   = (unsigned short*)(W8 + 5 * SLOT);
    unsigned short* vT   = (unsigned short*)(W8 + 6 * SLOT);
    unsigned short* wqb  = (unsigned short*)(W8 + 7 * SLOT);                  // 4 weight slots
    unsigned short* wkb  = (unsigned short*)(W8 + 7 * SLOT + 1179648);
    unsigned short* wvb  = (unsigned short*)(W8 + 7 * SLOT + 2 * 1179648);
    unsigned short* wfcb = (unsigned short*)(W8 + 7 * SLOT + 3 * 1179648);
    float* stats         = (float*)(W8 + 7 * SLOT + 4 * 1179648);             // 196608 B
    // overlays (sources dead by the time these are written):
    float* attn_out = (float*)(W8 + 0 * SLOT);   // over qb+kb  (dead after proj)
    float* fc_out   = (float*)(W8 + 2 * SLOT);   // over vb+qh  (dead after proj/attn_term)

    float* out   = (float*)d_out;                 // [b][l][768]
    float* fused = out + (size_t)PROJ_ELEMS;      // [h][b][l][t] fp32

    cvt_k<<<dim3(3072, 1, 3), 256, 0, stream>>>(q, k, v, v, qb, kb, vb, vb, PROJ_ELEMS);
    cvt_k<<<dim3(576, 1, 4), 256, 0, stream>>>(wq, wk, wv, wfc, wqb, wkb, wvb, wfcb,
                                               D_MODEL * D_MODEL);
    zero_stats<<<dim3(48), 256, 0, stream>>>(stats);
    proj_mfma<<<dim3(6, 32, 3), 256, 0, stream>>>(qb, kb, vb, wqb, wkb, wvb,
                                                  bq, bk, bv, qh, kh, vh);
    vtrans<<<dim3(16, HB), 256, 0, stream>>>(vh, vT);
    attn_term<<<dim3(16, 32, BATCH), 256, 0, stream>>>(qh, kh, pl, mask, wloc, bloc,
                                                       fused, stats);
    pv_scale<<<dim3(16, HB), 256, 0, stream>>>(fused, vT, stats, attn_out);
    fc_mfma<<<dim3(6, 32), 256, 0, stream>>>(attn_out, wfcb, bfc, q, fc_out);
    ln_k<<<dim3(BATCH * SEQ), 256, 0, stream>>>(fc_out, lng, lnb, out);
}